// Round 3
// baseline (26.296 us; speedup 1.0000x reference)
//
#include <hip/hip_runtime.h>
#include <math.h>

// Problem constants (from reference setup_inputs)
#define BS    16
#define NQ    100
#define Q_DIM (BS * NQ)        // 1600
#define T_DIM 320
#define P_DIM 72
#define ROW   (5 + 2 * P_DIM)  // 149 floats per tgt row

#define TT  64                 // t-tile per block
#define QPT 4                  // q per thread (4 waves x 4 = 16 q per block)

// Single fused kernel. Grid (100, 5), 256 threads.
//  A: float4 staging of this block's 64 tgt rows (fully coalesced, 16B-aligned)
//  B: valid-counts for ALL 320 rows via coalesced row reads + __ballot
//  C: parallel min-reduce -> s_min
//  E: per-wave-uniform q (scalar curve loads), lane-varying t
//     (LDS stride 149 = odd -> conflict-free), coalesced out writes.
__global__ __launch_bounds__(256) void cost_kernel(
    const float* __restrict__ logits,   // [Q,2]
    const float* __restrict__ curves,   // [Q,8]
    const float* __restrict__ tgt,      // [T,149]
    const int*   __restrict__ tgt_ids,  // [T]
    float*       __restrict__ out)      // [Q,T]
{
    alignas(16) __shared__ float s_tgt[TT * ROW];   // 38144 B
    __shared__ float s_vc[T_DIM];                   // 1280 B
    __shared__ float s_min;

    const int tx   = threadIdx.x;
    const int lane = tx & 63;
    const int wave = tx >> 6;               // 0..3
    const int t_base = blockIdx.y * TT;

    // ---- Phase A: float4 staging (38144 B = 2384 float4, exact) ----
    {
        const float4* src4 = reinterpret_cast<const float4*>(tgt + t_base * ROW);
        float4* dst4 = reinterpret_cast<float4*>(s_tgt);
        #pragma unroll
        for (int i = tx; i < (TT * ROW) / 4; i += 256) dst4[i] = src4[i];
    }

    // ---- Phase B: valid-counts for all 320 rows, coalesced + ballot ----
    // wave w handles rows [80w, 80w+80): lane l reads element l (contiguous).
    {
        const int t0 = wave * (T_DIM / 4);
        for (int r = 0; r < T_DIM / 4; ++r) {
            const int t = t0 + r;
            const float* row = tgt + t * ROW + 5;
            const bool v1 = row[lane] >= 0.0f;                       // elems 0..63
            const bool v2 = (lane < P_DIM - 64) && (row[64 + lane] >= 0.0f); // 64..71
            const unsigned long long m1 = __ballot(v1);
            const unsigned long long m2 = __ballot(v2);
            if (lane == 0)
                s_vc[t] = (float)(__popcll(m1) + __popcll(m2));
        }
    }
    __syncthreads();

    // ---- Phase C: parallel min-reduce over 320 counts ----
    if (tx < 64) {
        float m = s_vc[tx];
        #pragma unroll
        for (int k = 1; k < T_DIM / 64; ++k) m = fminf(m, s_vc[tx + k * 64]);
        #pragma unroll
        for (int d = 32; d > 0; d >>= 1) m = fminf(m, __shfl_xor(m, d, 64));
        if (tx == 0) s_min = m;
    }
    __syncthreads();

    // ---- Phase D: per-thread constants ----
    const int t = t_base + lane;
    const float* srow = s_tgt + lane * ROW;

    const float ly = srow[1], uy = srow[2], lx = srow[3], ux = srow[4];
    const int   id = tgt_ids[t];
    const float wt = sqrtf(s_min / s_vc[t]) * 0.1f;   // CURVES_W / 10

    const int q0 = blockIdx.x * (4 * QPT) + wave * QPT;

    float b0[QPT], b1[QPT], b2[QPT], b3[QPT], base_cost[QPT];
    #pragma unroll
    for (int j = 0; j < QPT; ++j) {
        const int q = q0 + j;
        const float* c = curves + q * 8;
        b0[j] = c[0]; b1[j] = c[1]; b2[j] = c[2]; b3[j] = c[3];
        const float b4 = c[4], b5 = c[5], b6 = c[6], b7 = c[7];
        const float l0 = logits[q * 2 + 0], l1 = logits[q * 2 + 1];
        const float m  = fmaxf(l0, l1);
        const float e0 = expf(l0 - m), e1 = expf(l1 - m);
        const float inv = 1.0f / (e0 + e1);
        const float prob = (id == 0) ? e0 * inv : e1 * inv;
        const float cl = (fabsf(b4 - ly) + fabsf(b6 - lx)) * 0.5f;
        const float cu = (fabsf(b5 - uy) + fabsf(b7 - ux)) * 0.5f;
        base_cost[j] = -prob + cl + cu;
    }

    // ---- Phase E: main p-loop ----
    float acc[QPT] = {0.0f, 0.0f, 0.0f, 0.0f};
    #pragma unroll 8
    for (int p = 0; p < P_DIM; ++p) {
        const float xs = srow[5 + p];              // ds_read2_b32 pair with ys
        const float ys = srow[5 + P_DIM + p];
        const float vmask = (xs >= 0.0f) ? 1.0f : 0.0f;
        #pragma unroll
        for (int j = 0; j < QPT; ++j) {
            const float v = ((b3[j] * ys + b2[j]) * ys + b1[j]) * ys + b0[j];
            acc[j] = fmaf(vmask, fabsf(xs - v), acc[j]);
        }
    }

    #pragma unroll
    for (int j = 0; j < QPT; ++j) {
        const int q = q0 + j;
        out[q * T_DIM + t] = base_cost[j] + acc[j] * wt;
    }
}

extern "C" void kernel_launch(void* const* d_in, const int* in_sizes, int n_in,
                              void* d_out, int out_size, void* d_ws, size_t ws_size,
                              hipStream_t stream) {
    const float* logits  = (const float*)d_in[0];  // [16,100,2]
    const float* curves  = (const float*)d_in[1];  // [16,100,8]
    const float* tgt     = (const float*)d_in[2];  // [320,149]
    const int*   tgt_ids = (const int*)d_in[3];    // [320]
    float* out = (float*)d_out;                    // [16,100,320]

    dim3 grid(Q_DIM / (4 * QPT), T_DIM / TT);      // (100, 5)
    cost_kernel<<<grid, 256, 0, stream>>>(logits, curves, tgt, tgt_ids, out);
}